// Round 5
// baseline (59545.758 us; speedup 1.0000x reference)
//
#include <hip/hip_runtime.h>
#include <hip/hip_cooperative_groups.h>

#define HID    512
#define TPB    512
#define NSTEP  60
#define BMI    64
#define NBLK   256

using f32x4 = __attribute__((ext_vector_type(4))) float;
using s16x8 = __attribute__((ext_vector_type(8))) short;

__device__ __forceinline__ unsigned short f2bf(float f) {
    unsigned u = __builtin_bit_cast(unsigned, f);
    u += 0x7fffu + ((u >> 16) & 1u);
    return (unsigned short)(u >> 16);
}
__device__ __forceinline__ float bf2f(unsigned u) {
    return __builtin_bit_cast(float, u << 16);
}
__device__ __forceinline__ float sigm(float x) { return 1.0f / (1.0f + __expf(-x)); }
__device__ __forceinline__ float tanh_(float x) { return 1.0f - 2.0f / (__expf(2.0f * x) + 1.0f); }

// XOR-gate un-permute: pa[g] = q[g ^ lgr], lgr wave-uniform
__device__ __forceinline__ f32x4 deperm(f32x4 q, int lgr) {
    f32x4 p;
    if (lgr == 0)      { p[0]=q[0]; p[1]=q[1]; p[2]=q[2]; p[3]=q[3]; }
    else if (lgr == 1) { p[0]=q[1]; p[1]=q[0]; p[2]=q[3]; p[3]=q[2]; }
    else if (lgr == 2) { p[0]=q[2]; p[1]=q[3]; p[2]=q[0]; p[3]=q[1]; }
    else               { p[0]=q[3]; p[1]=q[2]; p[2]=q[1]; p[3]=q[0]; }
    return p;
}

// ---------------- weight packing (identical to r3/r4 — verified) ----------------
__global__ void pack_kernel(const float* __restrict__ w_hh0, const float* __restrict__ w_ih1,
                            const float* __restrict__ w_hh1, const float* __restrict__ w_init_h,
                            const float* __restrict__ w_init_c,
                            const float* __restrict__ b_ih0, const float* __restrict__ b_hh0,
                            const float* __restrict__ b_ih1, const float* __restrict__ b_hh1,
                            unsigned short* __restrict__ PW1, unsigned short* __restrict__ PW2,
                            unsigned short* __restrict__ PI,
                            float* __restrict__ b1, float* __restrict__ b2)
{
    int idx = blockIdx.x * 256 + threadIdx.x;
    if (idx < 1048576) {
        int el = idx & 511, fr = idx >> 9;
        int ks = fr & 15, ct = (fr >> 4) & 7, s = fr >> 7;
        int lane = el >> 3, e = el & 7;
        int cl = ct * 16 + (lane & 15);
        int gcol = (cl >> 5) * 512 + s * 32 + (cl & 31);
        int k = ks * 32 + (lane >> 4) * 8 + e;
        PW1[idx] = f2bf(w_hh0[gcol * 512 + k]);
        return;
    }
    int i2 = idx - 1048576;
    if (i2 >= 0 && i2 < 2097152) {
        int el = i2 & 511, fr = i2 >> 9;
        int ks = fr & 31, ct = (fr >> 5) & 7, s = fr >> 8;
        int lane = el >> 3, e = el & 7;
        int cl = ct * 16 + (lane & 15);
        int gcol = (cl >> 5) * 512 + s * 32 + (cl & 31);
        int kk = (ks & 15) * 32 + (lane >> 4) * 8 + e;
        float v = (ks < 16) ? w_ih1[gcol * 512 + kk] : w_hh1[gcol * 512 + kk];
        PW2[i2] = f2bf(v);
        return;
    }
    int i3 = idx - (1048576 + 2097152);
    if (i3 >= 0 && i3 < 524288) {
        int el = i3 & 511, fr = i3 >> 9;
        int ks = fr & 15, tile = fr >> 4;
        int s = tile >> 5, c = tile & 31;
        int lane = el >> 3, e = el & 7;
        int n = c * 16 + (lane & 15);
        int k = ks * 32 + (lane >> 4) * 8 + e;
        float v = s ? w_init_c[n * 512 + k] : w_init_h[n * 512 + k];
        PI[i3] = f2bf(v);
        return;
    }
    int i4 = idx - (1048576 + 2097152 + 524288);
    if (i4 >= 0 && i4 < 2048) b1[i4] = b_ih0[i4] + b_hh0[i4];
    else if (i4 >= 2048 && i4 < 4096) b2[i4 - 2048] = b_ih1[i4 - 2048] + b_hh1[i4 - 2048];
}

// ---------------- init: writes BLOCK-MAJOR state layout [g*16+s][2048][32] ----------------
__global__ __launch_bounds__(TPB, 2) void init_kernel(
    const float* __restrict__ hin, const unsigned short* __restrict__ PI,
    const float* __restrict__ b_init_h, const float* __restrict__ b_init_c,
    unsigned short* __restrict__ h1s, unsigned short* __restrict__ h2s,
    unsigned short* __restrict__ c1s, unsigned short* __restrict__ c2s)
{
    __shared__ unsigned short bufA[BMI * HID];
    const int tid = threadIdx.x, lane = tid & 63, wave = tid >> 6;
    const int m0 = blockIdx.x * BMI;
    const int l15 = lane & 15, lg = lane >> 4;
    const int swz = (lane & 7) << 4;

    for (int j = 0; j < 16; ++j) {
        int e = tid * 4 + j * 2048;
        int row = e >> 9, col = e & 511;
        float4 v = *(const float4*)(hin + (size_t)(m0 + row) * HID + col);
        ushort4 w;
        w.x = f2bf(v.x); w.y = f2bf(v.y); w.z = f2bf(v.z); w.w = f2bf(v.w);
        int L = (row * 1024 + col * 2) ^ ((row & 7) << 4);
        *(ushort4*)((char*)bufA + L) = w;
    }
    __syncthreads();

    #pragma unroll 1
    for (int cc = 0; cc < 4; ++cc) {
        int c = wave * 4 + cc;
        int nc = c * 16 + l15;
        f32x4 acc[4][2];
        #pragma unroll
        for (int rt = 0; rt < 4; ++rt)
            #pragma unroll
            for (int s = 0; s < 2; ++s)
                #pragma unroll
                for (int r = 0; r < 4; ++r) acc[rt][s][r] = 0.0f;

        #pragma unroll
        for (int ks = 0; ks < 16; ++ks) {
            s16x8 a[4];
            #pragma unroll
            for (int rt = 0; rt < 4; ++rt) {
                int ao = (rt * 16 + l15) * 1024 + ((ks * 64 + lg * 16) ^ swz);
                a[rt] = *(const s16x8*)((const char*)bufA + ao);
            }
            #pragma unroll
            for (int s = 0; s < 2; ++s) {
                s16x8 b = ((const s16x8*)PI)[((s * 32 + c) * 16 + ks) * 64 + lane];
                #pragma unroll
                for (int rt = 0; rt < 4; ++rt)
                    acc[rt][s] = __builtin_amdgcn_mfma_f32_16x16x32_bf16(a[rt], b, acc[rt][s], 0, 0, 0);
            }
        }
        float bh = b_init_h[nc], bc = b_init_c[nc];
        int sl = nc >> 5, ul = nc & 31;
        #pragma unroll
        for (int rt = 0; rt < 4; ++rt)
            #pragma unroll
            for (int r = 0; r < 4; ++r) {
                int m = m0 + rt * 16 + lg * 4 + r;
                int gg = m >> 11, lr = m & 2047;
                float hv = acc[rt][0][r] + bh;
                float cv = acc[rt][1][r] + bc;
                unsigned short hb = f2bf(hv);
                size_t o = ((size_t)(gg * 16 + sl) * 2048 + lr) * 32 + ul;
                h1s[o] = hb; h2s[o] = hb;
                c1s[o] = f2bf(cv); c2s[o] = f2bf(cv);
            }
    }
}

// ---------------- persistent cooperative kernel: all 60 steps ----------------
__global__ __launch_bounds__(TPB, 2) void traj_kernel(
    unsigned short* __restrict__ h1a, unsigned short* __restrict__ h1b,
    unsigned short* __restrict__ h2a, unsigned short* __restrict__ h2b,
    unsigned short* __restrict__ c1s, unsigned short* __restrict__ c2s,
    float* __restrict__ pp,
    const unsigned short* __restrict__ PW1, const unsigned short* __restrict__ PW2,
    const float* __restrict__ b1, const float* __restrict__ b2,
    const float* __restrict__ w_ih0, const float* __restrict__ w_out,
    const float* __restrict__ b_out, float* __restrict__ outp)
{
    __shared__ __align__(16) unsigned short Ab[32768];   // 64 KB
    __shared__ __align__(16) float gl[2][2][2304];       // 36 KB
    __shared__ __align__(16) float xls[4160];            // 16.25 KB

    const int tid = threadIdx.x, lane = tid & 63, w = tid >> 6;
    const int b = blockIdx.x;
    const int g = 2 * (b & 7) + (b >> 7);
    const int s = (b >> 3) & 15;
    const int l15 = lane & 15, lg = lane >> 4;
    const int cg = w & 1, kh = (w >> 1) & 1, rha = w >> 2;   // phase-A wave roles
    const int kq = w >> 1;                                   // phase-B
    const int copy = kq >> 1, adder = ((kq & 1) == 0);

    const int erow = tid >> 4, ejp = tid & 15;
    const int lgr = w & 3;

    // staging decompose (both phases): LDS addr = p*8192 + tid*16
    const int st_ks  = tid >> 7;          // k-block quarter within pass
    const int st_rh  = (tid >> 6) & 1;
    const int st_lg  = (tid >> 4) & 3;
    const int st_l15 = tid & 15;

    const size_t grpOff = (size_t)g * 16 * 2048 * 32;    // group base (ushort units)
    const size_t blkOff = ((size_t)(g * 16 + s)) * 2048 * 32;

    const float bo0 = b_out[0], bo1 = b_out[1];
    const float woA0 = w_out[s * 32 + ejp * 2],       woA1 = w_out[s * 32 + ejp * 2 + 1];
    const float woB0 = w_out[512 + s * 32 + ejp * 2], woB1 = w_out[512 + s * 32 + ejp * 2 + 1];

    #pragma unroll 1
    for (int t = 0; t <= NSTEP; ++t) {
        unsigned short* h1R = (t & 1) ? h1a : h1b;   // slot (t+1)&1
        unsigned short* h1W = (t & 1) ? h1b : h1a;   // slot t&1
        unsigned short* h2R = (t & 1) ? h2a : h2b;
        unsigned short* h2W = (t & 1) ? h2b : h2a;

        // ---- inter-step: reduce pp -> xls (x incl. bias); write out[:, t-1] ----
        if (t == 0) {
            #pragma unroll
            for (int i = 0; i < 8; ++i) xls[tid * 8 + i] = 0.0f;
        } else {
            f32x4 s0 = {0.f,0.f,0.f,0.f}, s1 = {0.f,0.f,0.f,0.f};
            #pragma unroll 1
            for (int ss = 0; ss < 16; ++ss) {
                const float* p = pp + (((size_t)(g * 16 + ss)) << 12) + tid * 8;
                s0 += *(const f32x4*)p;
                s1 += *(const f32x4*)(p + 4);
            }
            s0[0] += bo0; s0[1] += bo1; s0[2] += bo0; s0[3] += bo1;
            s1[0] += bo0; s1[1] += bo1; s1[2] += bo0; s1[3] += bo1;
            *(f32x4*)(xls + tid * 8) = s0;
            *(f32x4*)(xls + tid * 8 + 4) = s1;
            if (s == 0) {
                float* ob = outp + (size_t)(g * 2048 + tid * 4) * (2 * NSTEP) + (t - 1) * 2;
                *(float2*)(ob)             = make_float2(s0[0], s0[1]);
                *(float2*)(ob + 2 * NSTEP) = make_float2(s0[2], s0[3]);
                *(float2*)(ob + 4 * NSTEP) = make_float2(s1[0], s1[1]);
                *(float2*)(ob + 6 * NSTEP) = make_float2(s1[2], s1[3]);
            }
        }
        if (t == NSTEP) break;

        // ================= phase A: layer 1 =================
        {
            float b1v[8], wiA[8], wiB[8];
            #pragma unroll
            for (int q = 0; q < 8; ++q) {
                int dj = q & 1, gq = q >> 1;
                int gcol = gq * 512 + s * 32 + ejp * 2 + dj;
                b1v[q] = b1[gcol];
                wiA[q] = w_ih0[gcol * 2 + 0];
                wiB[q] = w_ih0[gcol * 2 + 1];
            }
            s16x8 bw[4][8];
            #pragma unroll
            for (int j = 0; j < 4; ++j)
                #pragma unroll
                for (int ksl = 0; ksl < 8; ++ksl)
                    bw[j][ksl] = ((const s16x8*)PW1)[(((s * 8 + cg * 4 + j) * 16) + kh * 8 + ksl) * 64 + lane];

            const unsigned short* h1Rg = h1R + grpOff;

            uint4 nv[4];
            #pragma unroll
            for (int p = 0; p < 4; ++p) {
                int ks = p * 4 + st_ks;
                nv[p] = *(const uint4*)(h1Rg + ((size_t)ks * 2048 + st_rh * 16 + st_l15) * 32 + st_lg * 8);
            }
            #pragma unroll
            for (int p = 0; p < 4; ++p)
                *(uint4*)((char*)Ab + p * 8192 + tid * 16) = nv[p];

            #pragma unroll 1
            for (int ch = 0; ch < 64; ++ch) {
                __syncthreads();   // Ab + xls ready; prev epilogue done with gl

                if (ch < 63) {
                    #pragma unroll
                    for (int p = 0; p < 4; ++p) {
                        int ks = p * 4 + st_ks;
                        nv[p] = *(const uint4*)(h1Rg + ((size_t)ks * 2048 + (ch + 1) * 32 + st_rh * 16 + st_l15) * 32 + st_lg * 8);
                    }
                }

                f32x4 acc[4];
                #pragma unroll
                for (int j = 0; j < 4; ++j) { acc[j][0]=0.f; acc[j][1]=0.f; acc[j][2]=0.f; acc[j][3]=0.f; }
                #pragma unroll
                for (int ksl = 0; ksl < 8; ++ksl) {
                    int ks = kh * 8 + ksl;
                    s16x8 a = *(const s16x8*)((const char*)Ab + ks * 2048 + rha * 1024 + lane * 16);
                    #pragma unroll
                    for (int j = 0; j < 4; ++j)
                        acc[j] = __builtin_amdgcn_mfma_f32_16x16x32_bf16(a, bw[j][ksl], acc[j], 0, 0, 0);
                }
                #pragma unroll
                for (int j = 0; j < 4; ++j) {
                    int col = (cg * 4 + j) * 16 + l15;
                    int u = col & 31, gate = col >> 5;
                    float* dst = &gl[kh][u & 1][(u >> 1) * 4 + (gate ^ lg)];
                    #pragma unroll
                    for (int r = 0; r < 4; ++r)
                        dst[(rha * 16 + lg * 4 + r) * 64] = acc[j][r];
                }
                __syncthreads();   // gl complete; Ab reads done

                if (ch < 63) {
                    #pragma unroll
                    for (int p = 0; p < 4; ++p)
                        *(uint4*)((char*)Ab + p * 8192 + tid * 16) = nv[p];
                }

                {
                    int mloc = ch * 32 + erow;
                    float x0 = xls[mloc * 2 + 0], x1 = xls[mloc * 2 + 1];
                    int gbase = erow * 64 + ejp * 4;
                    f32x4 qa = *(const f32x4*)&gl[0][0][gbase];
                    qa += *(const f32x4*)&gl[1][0][gbase];
                    f32x4 qb = *(const f32x4*)&gl[0][1][gbase];
                    qb += *(const f32x4*)&gl[1][1][gbase];
                    qa = deperm(qa, lgr); qb = deperm(qb, lgr);

                    size_t cix = blkOff + (size_t)mloc * 32 + ejp * 2;
                    unsigned cp = *(const unsigned*)(c1s + cix);
                    float cold0 = bf2f(cp & 0xffffu), cold1 = bf2f(cp >> 16);
                    float i0 = sigm(qa[0] + b1v[0] + x0 * wiA[0] + x1 * wiB[0]);
                    float f0 = sigm(qa[1] + b1v[2] + x0 * wiA[2] + x1 * wiB[2]);
                    float g0 = tanh_(qa[2] + b1v[4] + x0 * wiA[4] + x1 * wiB[4]);
                    float o0 = sigm(qa[3] + b1v[6] + x0 * wiA[6] + x1 * wiB[6]);
                    float cn0 = f0 * cold0 + i0 * g0;
                    float hn0 = o0 * tanh_(cn0);
                    float i1 = sigm(qb[0] + b1v[1] + x0 * wiA[1] + x1 * wiB[1]);
                    float f1 = sigm(qb[1] + b1v[3] + x0 * wiA[3] + x1 * wiB[3]);
                    float g1 = tanh_(qb[2] + b1v[5] + x0 * wiA[5] + x1 * wiB[5]);
                    float o1 = sigm(qb[3] + b1v[7] + x0 * wiA[7] + x1 * wiB[7]);
                    float cn1 = f1 * cold1 + i1 * g1;
                    float hn1 = o1 * tanh_(cn1);
                    *(unsigned*)(c1s + cix) = (unsigned)f2bf(cn0) | ((unsigned)f2bf(cn1) << 16);
                    *(unsigned*)(h1W + cix) = (unsigned)f2bf(hn0) | ((unsigned)f2bf(hn1) << 16);
                }
            }
        }
        cooperative_groups::this_grid().sync();

        // ================= phase B: layer 2 =================
        {
            float b2v[8];
            #pragma unroll
            for (int q = 0; q < 8; ++q) {
                int dj = q & 1, gq = q >> 1;
                b2v[q] = b2[gq * 512 + s * 32 + ejp * 2 + dj];
            }
            s16x8 bw[4][8];
            #pragma unroll
            for (int j = 0; j < 4; ++j)
                #pragma unroll
                for (int ksl = 0; ksl < 8; ++ksl)
                    bw[j][ksl] = ((const s16x8*)PW2)[(((s * 8 + cg * 4 + j) * 32) + kq * 8 + ksl) * 64 + lane];

            const unsigned short* h1Cg = h1W + grpOff;
            const unsigned short* h2Rg = h2R + grpOff;

            uint4 nv[8];
            #pragma unroll
            for (int p = 0; p < 8; ++p) {
                int ks = p * 4 + st_ks;
                const unsigned short* sb = (ks < 16) ? (h1Cg + (size_t)ks * 2048 * 32)
                                                     : (h2Rg + (size_t)(ks - 16) * 2048 * 32);
                nv[p] = *(const uint4*)(sb + ((size_t)(st_rh * 16 + st_l15)) * 32 + st_lg * 8);
            }
            #pragma unroll
            for (int p = 0; p < 8; ++p)
                *(uint4*)((char*)Ab + p * 8192 + tid * 16) = nv[p];

            #pragma unroll 1
            for (int ch = 0; ch < 64; ++ch) {
                __syncthreads();

                if (ch < 63) {
                    #pragma unroll
                    for (int p = 0; p < 8; ++p) {
                        int ks = p * 4 + st_ks;
                        const unsigned short* sb = (ks < 16) ? (h1Cg + (size_t)ks * 2048 * 32)
                                                             : (h2Rg + (size_t)(ks - 16) * 2048 * 32);
                        nv[p] = *(const uint4*)(sb + ((size_t)((ch + 1) * 32) + st_rh * 16 + st_l15) * 32 + st_lg * 8);
                    }
                }

                f32x4 acc[2][4];
                #pragma unroll
                for (int rh = 0; rh < 2; ++rh)
                    #pragma unroll
                    for (int j = 0; j < 4; ++j) { acc[rh][j][0]=0.f; acc[rh][j][1]=0.f; acc[rh][j][2]=0.f; acc[rh][j][3]=0.f; }
                #pragma unroll
                for (int ksl = 0; ksl < 8; ++ksl) {
                    int ks = kq * 8 + ksl;
                    s16x8 a0 = *(const s16x8*)((const char*)Ab + ks * 2048 + lane * 16);
                    s16x8 a1 = *(const s16x8*)((const char*)Ab + ks * 2048 + 1024 + lane * 16);
                    #pragma unroll
                    for (int j = 0; j < 4; ++j) {
                        acc[0][j] = __builtin_amdgcn_mfma_f32_16x16x32_bf16(a0, bw[j][ksl], acc[0][j], 0, 0, 0);
                        acc[1][j] = __builtin_amdgcn_mfma_f32_16x16x32_bf16(a1, bw[j][ksl], acc[1][j], 0, 0, 0);
                    }
                }

                if (!adder) {
                    #pragma unroll
                    for (int j = 0; j < 4; ++j) {
                        int col = (cg * 4 + j) * 16 + l15;
                        int u = col & 31, gate = col >> 5;
                        float* dst = &gl[copy][u & 1][(u >> 1) * 4 + (gate ^ lg)];
                        #pragma unroll
                        for (int rh = 0; rh < 2; ++rh)
                            #pragma unroll
                            for (int r = 0; r < 4; ++r)
                                dst[(rh * 16 + lg * 4 + r) * 64] = acc[rh][j][r];
                    }
                }
                __syncthreads();
                if (adder) {
                    #pragma unroll
                    for (int j = 0; j < 4; ++j) {
                        int col = (cg * 4 + j) * 16 + l15;
                        int u = col & 31, gate = col >> 5;
                        float* dst = &gl[copy][u & 1][(u >> 1) * 4 + (gate ^ lg)];
                        #pragma unroll
                        for (int rh = 0; rh < 2; ++rh)
                            #pragma unroll
                            for (int r = 0; r < 4; ++r)
                                dst[(rh * 16 + lg * 4 + r) * 64] += acc[rh][j][r];
                    }
                }
                __syncthreads();

                if (ch < 63) {
                    #pragma unroll
                    for (int p = 0; p < 8; ++p)
                        *(uint4*)((char*)Ab + p * 8192 + tid * 16) = nv[p];
                }

                {
                    int mloc = ch * 32 + erow;
                    int gbase = erow * 64 + ejp * 4;
                    f32x4 qa = *(const f32x4*)&gl[0][0][gbase];
                    qa += *(const f32x4*)&gl[1][0][gbase];
                    f32x4 qb = *(const f32x4*)&gl[0][1][gbase];
                    qb += *(const f32x4*)&gl[1][1][gbase];
                    qa = deperm(qa, lgr); qb = deperm(qb, lgr);

                    size_t cix = blkOff + (size_t)mloc * 32 + ejp * 2;
                    unsigned cp = *(const unsigned*)(c2s + cix);
                    float cold0 = bf2f(cp & 0xffffu), cold1 = bf2f(cp >> 16);
                    float i0 = sigm(qa[0] + b2v[0]);
                    float f0 = sigm(qa[1] + b2v[2]);
                    float g0 = tanh_(qa[2] + b2v[4]);
                    float o0 = sigm(qa[3] + b2v[6]);
                    float cn0 = f0 * cold0 + i0 * g0;
                    float hn0 = o0 * tanh_(cn0);
                    float i1 = sigm(qb[0] + b2v[1]);
                    float f1 = sigm(qb[1] + b2v[3]);
                    float g1 = tanh_(qb[2] + b2v[5]);
                    float o1 = sigm(qb[3] + b2v[7]);
                    float cn1 = f1 * cold1 + i1 * g1;
                    float hn1 = o1 * tanh_(cn1);
                    *(unsigned*)(c2s + cix) = (unsigned)f2bf(cn0) | ((unsigned)f2bf(cn1) << 16);
                    *(unsigned*)(h2W + cix) = (unsigned)f2bf(hn0) | ((unsigned)f2bf(hn1) << 16);

                    float p0 = hn0 * woA0 + hn1 * woA1;
                    float p1 = hn0 * woB0 + hn1 * woB1;
                    #pragma unroll
                    for (int d = 1; d < 16; d <<= 1) {
                        p0 += __shfl_xor(p0, d, 16);
                        p1 += __shfl_xor(p1, d, 16);
                    }
                    if (ejp == 0)
                        *(float2*)(pp + (((size_t)(g * 16 + s)) << 12) + (size_t)mloc * 2)
                            = make_float2(p0, p1);
                }
            }
        }
        cooperative_groups::this_grid().sync();
    }
}

extern "C" void kernel_launch(void* const* d_in, const int* in_sizes, int n_in,
                              void* d_out, int out_size, void* d_ws, size_t ws_size,
                              hipStream_t stream)
{
    (void)in_sizes; (void)n_in; (void)out_size; (void)ws_size;
    const float* h        = (const float*)d_in[0];
    const float* w_init_h = (const float*)d_in[1];
    const float* b_init_h = (const float*)d_in[2];
    const float* w_init_c = (const float*)d_in[3];
    const float* b_init_c = (const float*)d_in[4];
    const float* w_ih0    = (const float*)d_in[5];
    const float* w_hh0    = (const float*)d_in[6];
    const float* b_ih0    = (const float*)d_in[7];
    const float* b_hh0    = (const float*)d_in[8];
    const float* w_ih1    = (const float*)d_in[9];
    const float* w_hh1    = (const float*)d_in[10];
    const float* b_ih1    = (const float*)d_in[11];
    const float* b_hh1    = (const float*)d_in[12];
    const float* w_out    = (const float*)d_in[13];
    const float* b_out    = (const float*)d_in[14];
    float* out = (float*)d_out;

    char* ws = (char*)d_ws;
    unsigned short* h1a = (unsigned short*)(ws + 0);          // slot 0
    unsigned short* h1b = (unsigned short*)(ws + 33554432);   // slot 1
    unsigned short* h2a = (unsigned short*)(ws + 67108864);
    unsigned short* h2b = (unsigned short*)(ws + 100663296);
    unsigned short* c1s = (unsigned short*)(ws + 134217728);
    unsigned short* c2s = (unsigned short*)(ws + 167772160);
    float* pp           = (float*)(ws + 201326592);           // 4 MB
    unsigned short* PW1 = (unsigned short*)(ws + 205520896);
    unsigned short* PW2 = (unsigned short*)(ws + 207618048);
    unsigned short* PI  = (unsigned short*)(ws + 211812352);
    float* b1 = (float*)(ws + 212860928);
    float* b2 = (float*)(ws + 212869120);

    pack_kernel<<<14352, 256, 0, stream>>>(w_hh0, w_ih1, w_hh1, w_init_h, w_init_c,
                                           b_ih0, b_hh0, b_ih1, b_hh1, PW1, PW2, PI, b1, b2);
    // init writes ping-pong slot 1 (read at t=0)
    init_kernel<<<32768 / BMI, TPB, 0, stream>>>(h, PI, b_init_h, b_init_c,
                                                 h1b, h2b, c1s, c2s);
    void* args[] = { &h1a, &h1b, &h2a, &h2b, &c1s, &c2s, &pp, &PW1, &PW2,
                     &b1, &b2, &w_ih0, &w_out, &b_out, &out };
    hipLaunchCooperativeKernel((void*)traj_kernel, dim3(NBLK), dim3(TPB), args, 0, stream);
}